// Round 10
// baseline (383.044 us; speedup 1.0000x reference)
//
#include <hip/hip_runtime.h>
#include <math.h>

#define B_DIM 128
#define T_DIM 50
#define LEAF  4880
#define A_DIM 64
#define ATTN  128
#define RNN   128
#define NC    283
#define M_TOT (B_DIM*T_DIM)   // 6400
#define KSPLIT 10
#define NCH 153               // ceil(4880/32); chunk 152 has 16 valid k
#define WT_PLANE (NCH*512*8)  // 626688 ushort per plane (hi / lo)

using short8 = __attribute__((ext_vector_type(8))) short;
using short4v = __attribute__((ext_vector_type(4))) short;
using f32x4  = __attribute__((ext_vector_type(4))) float;

__device__ __forceinline__ float sigmoidf_(float x) {
  return 1.0f / (1.0f + __expf(-x));
}
// Fast tanh for the GRU's serial critical path (R14-proven safe).
__device__ __forceinline__ float tanhf_fast(float x) {
  x = fminf(fmaxf(x, -15.f), 15.f);
  float e = __expf(2.f * x);
  return (e - 1.f) * __builtin_amdgcn_rcpf(e + 1.f);
}

// RNE fp32 -> bf16 bits
__device__ __forceinline__ unsigned short f32_to_bf16_rne(float f) {
  unsigned int u = __float_as_uint(f);
  unsigned int r = u + 0x7FFFu + ((u >> 16) & 1u);
  return (unsigned short)(r >> 16);
}
__device__ __forceinline__ float bf16_bits_to_f32(unsigned short b) {
  return __uint_as_float(((unsigned int)b) << 16);
}

// ---------------------------------------------------------------------------
// Unified prep: (a) W[4880,128] -> Wt MFMA B-fragment order (hi/lo planes),
// (b) Wih0/Wih1/fc_w -> Bt0/Bt1/Bt2 fragment order for bn-MFMA (nt padded
// to 24; n >= N rows zeroed so padded tiles are inert).
// ---------------------------------------------------------------------------
__global__ __launch_bounds__(256) void k_prep(
    const float* __restrict__ Wd,
    const float* __restrict__ Wih0, const float* __restrict__ Wih1,
    const float* __restrict__ fcw,
    unsigned short* __restrict__ Wt,
    unsigned short* __restrict__ Bt0, unsigned short* __restrict__ Bt1,
    unsigned short* __restrict__ Bt2) {
  const int bx = blockIdx.x;
  const int tid = threadIdx.x;
  if (bx < 306) {
    const int u = bx * 256 + tid;   // 0 .. 78335 (NCH*512)
    const int c = u >> 9, rem = u & 511;
    const int nt = rem >> 6, lane = rem & 63;
    const int n = nt * 16 + (lane & 15);
    const int kb = c * 32 + ((lane >> 4) << 3);
    short8 h8, l8;
    #pragma unroll
    for (int j = 0; j < 8; ++j) {
      int k = kb + j;
      float v = (k < LEAF) ? Wd[(size_t)k * 128 + n] : 0.0f;
      unsigned short hb = f32_to_bf16_rne(v);
      unsigned short lb = f32_to_bf16_rne(v - bf16_bits_to_f32(hb));
      h8[j] = (short)hb;
      l8[j] = (short)lb;
    }
    *(short8*)&Wt[(size_t)u * 8] = h8;
    *(short8*)&Wt[(size_t)WT_PLANE + (size_t)u * 8] = l8;
  } else {
    const float* src; unsigned short* dst; int N, K, s0;
    if (bx < 330)      { src = Wih0; dst = Bt0; N = 384; K = 128; s0 = (bx - 306) * 256; }
    else if (bx < 354) { src = Wih1; dst = Bt1; N = 384; K = 128; s0 = (bx - 330) * 256; }
    else               { src = fcw;  dst = Bt2; N = NC;  K = 256; s0 = (bx - 354) * 256; }
    const int s = s0 + tid;
    const int PL = (K / 32) * 24 * 512;
    const int kc = s / (24 * 64);
    const int r  = s % (24 * 64);
    const int nt = r >> 6, lane = r & 63;
    const int n  = nt * 16 + (lane & 15);
    const int kb = kc * 32 + ((lane >> 4) << 3);
    short8 h8, l8;
    #pragma unroll
    for (int j = 0; j < 8; ++j) {
      float v = (n < N) ? src[(size_t)n * K + kb + j] : 0.0f;
      unsigned short hb = f32_to_bf16_rne(v);
      unsigned short lb = f32_to_bf16_rne(v - bf16_bits_to_f32(hb));
      h8[j] = (short)hb;
      l8[j] = (short)lb;
    }
    *(short8*)&dst[(size_t)s * 8] = h8;
    *(short8*)&dst[(size_t)PL + (size_t)s * 8] = l8;
  }
}

// ---------------------------------------------------------------------------
// Big GEMM via MFMA, v8 (R14: structural floor confirmed -- v5/v6/v7/v8 all
// equivalent; occupancy/LDS/prefetch levers exhausted). BM=64, KSPLIT=10,
// 1000 blocks, 4 blocks/CU. 3-MFMA hi/lo -> absmax bit-identical.
// ---------------------------------------------------------------------------
__global__ __launch_bounds__(512, 8) void k_gemm_mfma(
    const float* __restrict__ Ax, const unsigned short* __restrict__ Wt,
    float* __restrict__ P) {
  __shared__ __align__(16) unsigned short As[2][4096];  // 16 KB [buf][plane*2048 + frag]
  const int tid  = threadIdx.x;
  const int lane = tid & 63;
  const int w    = tid >> 6;     // wave id = nt tile (16 cols each)
  const int M0   = blockIdx.x * 64;
  const int s    = blockIdx.y;
  const int c0   = (s * NCH) / KSPLIT;
  const int c1   = ((s + 1) * NCH) / KSPLIT;

  const int am = tid >> 3;
  const int kq = tid & 7;
  const float* pA = Ax + (size_t)(M0 + am) * LEAF;
  const int a_idx = (am >> 4) * 512 + ((am & 15) + 16 * (kq >> 1)) * 8 + (kq & 1) * 4;

  f32x4 acc[4];
  #pragma unroll
  for (int i = 0; i < 4; ++i) {
    #pragma unroll
    for (int q = 0; q < 4; ++q) acc[i][q] = 0.0f;
  }

  float4 rA_a, rA_b;                 // ping-pong A prefetch (depth 2)
  short8 bh_a, bl_a, bh_b, bl_b;     // ping-pong B fragments (depth 1)

  auto issueB = [&](int c, short8& bh, short8& bl) {
    const size_t o = ((size_t)c * 512 + w * 64 + lane) * 8;
    bh = *(const short8*)&Wt[o];
    bl = *(const short8*)&Wt[(size_t)WT_PLANE + o];
  };
  auto issueA = [&](int c, float4& ra) {
    int kk = c * 32 + kq * 4;
    kk = min(kk, LEAF - 4);            // clamp (no skip): uniform vmcnt counts;
    ra = *(const float4*)(pA + kk);    // clamped dup data x Wt zero rows = 0
  };
  auto storeA = [&](int p, float4 ra) {
    float v[4] = {ra.x, ra.y, ra.z, ra.w};
    short4v h4, l4;
    #pragma unroll
    for (int j = 0; j < 4; ++j) {
      unsigned short hb = f32_to_bf16_rne(v[j]);
      unsigned short lb = f32_to_bf16_rne(v[j] - bf16_bits_to_f32(hb));
      h4[j] = (short)hb;
      l4[j] = (short)lb;
    }
    *(short4v*)&As[p][a_idx] = h4;
    *(short4v*)&As[p][2048 + a_idx] = l4;
  };
  auto compute = [&](int p, const short8& bh, const short8& bl) {
    #pragma unroll
    for (int m = 0; m < 4; ++m) {
      short8 a_hi = *(const short8*)&As[p][m * 512 + lane * 8];
      short8 a_lo = *(const short8*)&As[p][2048 + m * 512 + lane * 8];
      acc[m] = __builtin_amdgcn_mfma_f32_16x16x32_bf16(a_hi, bl, acc[m], 0, 0, 0);
      acc[m] = __builtin_amdgcn_mfma_f32_16x16x32_bf16(a_lo, bh, acc[m], 0, 0, 0);
      acc[m] = __builtin_amdgcn_mfma_f32_16x16x32_bf16(a_hi, bh, acc[m], 0, 0, 0);
    }
  };

  // ---- prologue ----
  {
    float4 ta;
    issueA(c0, ta);
    asm volatile("s_waitcnt vmcnt(0)" ::: "memory");
    storeA(0, ta);
    issueB(c0, bh_a, bl_a);                      // 2 loads
    asm volatile("" ::: "memory");
    if (c0 + 1 < c1) issueA(c0 + 1, rA_a);       // 1 load
    asm volatile("s_waitcnt lgkmcnt(0)" ::: "memory");
    __builtin_amdgcn_s_barrier();
    asm volatile("" ::: "memory");
    // outstanding entering loop: [B(c0) x2, A(c0+1)]
  }

#define GEMM_ITER(BHc, BLc, BHn, BLn, RAc, RAn)                               \
  {                                                                           \
    const int p = (c - c0) & 1;                                               \
    const bool has1 = (c + 1 < c1), has2 = (c + 2 < c1);                      \
    if (has1) { issueB(c + 1, BHn, BLn); asm volatile("" ::: "memory"); }     \
    if (has2) { issueA(c + 2, RAn);      asm volatile("" ::: "memory"); }     \
    if (has1) {                                                               \
      if (has2) { asm volatile("s_waitcnt vmcnt(3)" ::: "memory"); }          \
      else      { asm volatile("s_waitcnt vmcnt(2)" ::: "memory"); }          \
    } else      { asm volatile("s_waitcnt vmcnt(0)" ::: "memory"); }          \
    compute(p, BHc, BLc);                                                     \
    if (has1) storeA(p ^ 1, RAc);                                             \
    asm volatile("s_waitcnt lgkmcnt(0)" ::: "memory");                        \
    __builtin_amdgcn_s_barrier();                                             \
    asm volatile("" ::: "memory");                                            \
    ++c;                                                                      \
  }

  int c = c0;
  while (c < c1) {
    GEMM_ITER(bh_a, bl_a, bh_b, bl_b, rA_a, rA_b);
    if (c < c1) GEMM_ITER(bh_b, bl_b, bh_a, bl_a, rA_b, rA_a);
  }
#undef GEMM_ITER

  float* outp = P + (size_t)s * ((size_t)M_TOT * 128);
  const int col0 = w * 16 + (lane & 15);
  #pragma unroll
  for (int m = 0; m < 4; ++m) {
    const int rbase = M0 + m * 16 + ((lane >> 4) << 2);
    #pragma unroll
    for (int r = 0; r < 4; ++r)
      outp[(size_t)(rbase + r) * 128 + col0] = acc[m][r];
  }
}

// ---------------------------------------------------------------------------
// bn-MFMA (R13-proven). MODE 0: A0[M,K] plain. MODE 1 (R15): A-stage reads
// the 10 P partials, sums (same order as old k_reduce_tanh -> bit-identical)
// + tanh -- the reduce kernel and the X round-trip are eliminated. MODE 2
// (R15): K=256 split sources -- k<128 from A0 (=H2), k>=128 from A1 (=Katt);
// the S concat buffer is eliminated. Grid (3,400): the 3 nt-blocks sharing
// an m-tile are adjacent -> L2 hits on repeated A reads.
// ---------------------------------------------------------------------------
template<int KC, int ACT, int MODE>
__global__ __launch_bounds__(512) void k_bn_mfma(
    const float* __restrict__ A0, const float* __restrict__ A1,
    const unsigned short* __restrict__ Bt,
    const float* __restrict__ bias, const float* __restrict__ maskv,
    float* __restrict__ C, int N, int ldc) {
  constexpr int K  = KC * 32;
  constexpr int PL = KC * 24 * 512;     // ushorts per Bt plane
  __shared__ __align__(16) unsigned short As2[2][KC * 512];  // hi/lo planes
  const int tid  = threadIdx.x;
  const int lane = tid & 63;
  const int w    = tid >> 6;
  const int nt   = blockIdx.x * 8 + w;
  const int mrow = blockIdx.y * 16;

  short8 bh[KC], bl[KC];
  #pragma unroll
  for (int kc = 0; kc < KC; ++kc) {
    const size_t o = ((size_t)(kc * 24 + nt) * 64 + lane) * 8;
    bh[kc] = *(const short8*)&Bt[o];
    bl[kc] = *(const short8*)&Bt[(size_t)PL + o];
  }

  const int am = tid >> 5;
  const int q0 = tid & 31;
  constexpr int NQ = K / 128;           // float4 loads per thread (1 or 2)
  float4 av[NQ];
  if (MODE == 1) {
    // fused split-K reduce + tanh (identical sum order to old k_reduce_tanh)
    const float* p = A0 + (size_t)(mrow + am) * 128 + q0 * 4;
    float4 a = *(const float4*)p;
    #pragma unroll
    for (int s = 1; s < KSPLIT; ++s) {
      float4 b = *(const float4*)(p + (size_t)s * (M_TOT * 128));
      a.x += b.x; a.y += b.y; a.z += b.z; a.w += b.w;
    }
    av[0].x = tanhf(a.x); av[0].y = tanhf(a.y);
    av[0].z = tanhf(a.z); av[0].w = tanhf(a.w);
  } else if (MODE == 2) {
    av[0] = *(const float4*)&A0[(size_t)(mrow + am) * 128 + q0 * 4];
    av[1] = *(const float4*)&A1[(size_t)(mrow + am) * 128 + q0 * 4];
  } else {
    #pragma unroll
    for (int i = 0; i < NQ; ++i)
      av[i] = *(const float4*)&A0[(size_t)(mrow + am) * K + (q0 + 32 * i) * 4];
  }
  #pragma unroll
  for (int i = 0; i < NQ; ++i) {
    const int q = q0 + 32 * i;
    const int base = (am + 16 * (q >> 1)) * 8 + (q & 1) * 4;
    float v[4] = {av[i].x, av[i].y, av[i].z, av[i].w};
    short4v h4, l4;
    #pragma unroll
    for (int j = 0; j < 4; ++j) {
      unsigned short hb = f32_to_bf16_rne(v[j]);
      unsigned short lb = f32_to_bf16_rne(v[j] - bf16_bits_to_f32(hb));
      h4[j] = (short)hb;
      l4[j] = (short)lb;
    }
    *(short4v*)&As2[0][base] = h4;
    *(short4v*)&As2[1][base] = l4;
  }
  __syncthreads();

  f32x4 acc;
  #pragma unroll
  for (int q = 0; q < 4; ++q) acc[q] = 0.0f;
  #pragma unroll
  for (int kc = 0; kc < KC; ++kc) {
    const int slot = (lane & 15) + 64 * kc + 16 * (lane >> 4);
    short8 a_hi = *(const short8*)&As2[0][slot * 8];
    short8 a_lo = *(const short8*)&As2[1][slot * 8];
    acc = __builtin_amdgcn_mfma_f32_16x16x32_bf16(a_hi, bl[kc], acc, 0, 0, 0);
    acc = __builtin_amdgcn_mfma_f32_16x16x32_bf16(a_lo, bh[kc], acc, 0, 0, 0);
    acc = __builtin_amdgcn_mfma_f32_16x16x32_bf16(a_hi, bh[kc], acc, 0, 0, 0);
  }

  const int col = nt * 16 + (lane & 15);
  if (col < N) {
    const float bv = bias[col];
    #pragma unroll
    for (int r = 0; r < 4; ++r) {
      const int m = mrow + ((lane >> 4) << 2) + r;
      float v = acc[r] + bv;
      if (ACT) v = sigmoidf_(v) * maskv[m];
      C[(size_t)m * ldc + col] = v;
    }
  }
}

// ---------------------------------------------------------------------------
// GRU scan v3.1 (R5-proven structure + fast tanh; near its VALU-issue floor
// per R14 accounting). One block per batch row; 512 threads.
// ---------------------------------------------------------------------------
__global__ __launch_bounds__(512) void k_gru(
    const float* __restrict__ xW, const float* __restrict__ Whh,
    const float* __restrict__ bhh, float* __restrict__ Hout) {
  const int b = blockIdx.x;
  const int tid = threadIdx.x;
  const int j  = tid >> 2;
  const int qf = tid & 3;
  __shared__ __align__(16) float hs[2][128];

  float4 wr[8], wz[8], wn[8];
  {
    const float* pr = Whh + (size_t)j * 128 + qf * 32;
    const float* pz = Whh + (size_t)(j + 128) * 128 + qf * 32;
    const float* pn = Whh + (size_t)(j + 256) * 128 + qf * 32;
    #pragma unroll
    for (int k = 0; k < 8; ++k) {
      const int c = (k + qf * 2) & 7;   // rotation folded into the LOAD
      wr[k] = *(const float4*)(pr + c * 4);
      wz[k] = *(const float4*)(pz + c * 4);
      wn[k] = *(const float4*)(pn + c * 4);
    }
  }
  const float br = bhh[j], bz = bhh[j + 128], bn_ = bhh[j + 256];

  if (tid < 128) hs[0][tid] = 0.0f;
  const float* xwb = xW + (size_t)b * 50 * 384;
  float xr = 0.f, xz = 0.f, xn = 0.f;
  if (qf == 0) { xr = xwb[j]; xz = xwb[128 + j]; xn = xwb[256 + j]; }
  __syncthreads();

  int cur = 0;
  for (int t = 0; t < 50; ++t) {
    float nxr = 0.f, nxz = 0.f, nxn = 0.f;
    if (qf == 0 && t + 1 < 50) {
      const float* xwn = xwb + (size_t)(t + 1) * 384;
      nxr = xwn[j]; nxz = xwn[128 + j]; nxn = xwn[256 + j];
    }

    float ar = 0.f, az = 0.f, an = 0.f;
    #pragma unroll
    for (int k = 0; k < 8; ++k) {
      const int c = (k + qf * 2) & 7;   // runtime -> LDS address only
      float4 hv = *(const float4*)&hs[cur][qf * 32 + c * 4];
      ar += wr[k].x * hv.x + wr[k].y * hv.y + wr[k].z * hv.z + wr[k].w * hv.w;
      az += wz[k].x * hv.x + wz[k].y * hv.y + wz[k].z * hv.z + wz[k].w * hv.w;
      an += wn[k].x * hv.x + wn[k].y * hv.y + wn[k].z * hv.z + wn[k].w * hv.w;
    }
    ar += __shfl_xor(ar, 1); ar += __shfl_xor(ar, 2);
    az += __shfl_xor(az, 1); az += __shfl_xor(az, 2);
    an += __shfl_xor(an, 1); an += __shfl_xor(an, 2);

    if (qf == 0) {
      float r = sigmoidf_(xr + ar + br);
      float z = sigmoidf_(xz + az + bz);
      float nn = tanhf_fast(xn + r * (an + bn_));   // bias INSIDE r*
      float h = (1.f - z) * nn + z * hs[cur][j];
      hs[cur ^ 1][j] = h;
      Hout[(size_t)(b * 50 + t) * 128 + j] = h;
    }
    __syncthreads();
    cur ^= 1;
    xr = nxr; xz = nxz; xn = nxn;
  }
}

// ---------------------------------------------------------------------------
// Attention v2 (R15, flash-style): no Ls staging. emb (373 KB) is L2-hot;
// pass1 dots read emb rows straight from global, pass2 re-gathers for kv.
// LDS 35 KB -> ~1.3 KB: blocks/CU 4 -> 16 (wave-limited), latency hidden.
// 2x L2 gather traffic (~420 MB agg ~= 12us at L2 ceiling) -- was latency-
// bound, not BW-bound. Writes only Katt (H2 half of old S read directly by
// bn#3 MODE 2). FP order identical to v1 -> absmax unchanged.
// ---------------------------------------------------------------------------
__global__ __launch_bounds__(128) void k_attn(
    const float* __restrict__ H2, const int* __restrict__ F,
    const float* __restrict__ emb, float* __restrict__ Katt) {
  const int m = blockIdx.x;
  const int tid = threadIdx.x;
  __shared__ __align__(16) float outs[128];
  __shared__ float hls[64];
  __shared__ float wts[64];
  __shared__ int fs[64];

  outs[tid] = H2[(size_t)m * 128 + tid];
  if (tid < 64) fs[tid] = F[(size_t)m * 64 + tid];
  __syncthreads();

  // pass 1: hl[a] dots straight from L2-resident emb
  {
    const int a = tid >> 1, hf = tid & 1;
    const float* er = emb + (size_t)fs[a] * 128 + hf * 64;
    float sum = 0.f;
    #pragma unroll
    for (int j = 0; j < 16; ++j) {
      float4 lv = *(const float4*)&er[j * 4];
      float4 ov = *(const float4*)&outs[hf * 64 + j * 4];
      sum += lv.x * ov.x + lv.y * ov.y + lv.z * ov.z + lv.w * ov.w;
    }
    float other = __shfl_xor(sum, 1);
    sum += other;
    if (hf == 0) hls[a] = sum + (fs[a] > 0 ? 0.0f : -1e30f);
  }
  __syncthreads();

  if (tid < 64) {
    float v = hls[tid];
    float mx = v;
    #pragma unroll
    for (int o = 32; o; o >>= 1) mx = fmaxf(mx, __shfl_xor(mx, o));
    float e = __expf(v - mx);
    float sm = e;
    #pragma unroll
    for (int o = 32; o; o >>= 1) sm += __shfl_xor(sm, o);
    wts[tid] = e / sm;
  }
  __syncthreads();

  // pass 2: kv via per-a coalesced column gather (lane tid -> col tid)
  float kv = 0.f;
  #pragma unroll 8
  for (int a2 = 0; a2 < 64; ++a2)
    kv += wts[a2] * emb[(size_t)fs[a2] * 128 + tid];

  Katt[(size_t)m * 128 + tid] = kv;
}

// ---------------------------------------------------------------------------
extern "C" void kernel_launch(void* const* d_in, const int* in_sizes, int n_in,
                              void* d_out, int out_size, void* d_ws, size_t ws_size,
                              hipStream_t stream) {
  const float* inputs_x  = (const float*)d_in[0];
  const int*   inputs_f  = (const int*)d_in[1];
  const float* mask_seqs = (const float*)d_in[2];
  const float* dag_emb   = (const float*)d_in[3];
  const float* embed_a   = (const float*)d_in[4];
  const float* Wih0 = (const float*)d_in[5];
  const float* Whh0 = (const float*)d_in[6];
  const float* bih0 = (const float*)d_in[7];
  const float* bhh0 = (const float*)d_in[8];
  const float* Wih1 = (const float*)d_in[9];
  const float* Whh1 = (const float*)d_in[10];
  const float* bih1 = (const float*)d_in[11];
  const float* bhh1 = (const float*)d_in[12];
  const float* fc_w = (const float*)d_in[13];
  const float* fc_b = (const float*)d_in[14];
  float* out = (float*)d_out;

  float* ws = (float*)d_ws;
  // P: 10 slots of 819200 (live until bn#1 completes -- MODE 1 reads them).
  // Katt aliases P slot 1 (P dead by the time attn runs). xW/H1/H2 follow;
  // Wt (5MB bf16) aliases H1 (dead before gru writes H1; H2 is beyond Wt).
  // Bt0/1/2 after H2.
  float* P    = ws;
  float* Katt = P + 819200;
  float* xW = ws + KSPLIT * 819200;
  float* H1 = xW + 2457600;
  float* H2 = H1 + 819200;
  unsigned short* Wt  = (unsigned short*)H1;
  unsigned short* Bt0 = (unsigned short*)(H2 + 819200);   // 2*49152 ushorts
  unsigned short* Bt1 = Bt0 + 2 * 49152;                  // 2*49152
  unsigned short* Bt2 = Bt1 + 2 * 49152;                  // 2*98304

  k_prep<<<402, 256, 0, stream>>>(dag_emb, Wih0, Wih1, fc_w, Wt, Bt0, Bt1, Bt2);
  k_gemm_mfma<<<dim3(100, KSPLIT), 512, 0, stream>>>(inputs_x, Wt, P);
  k_bn_mfma<4, 0, 1><<<dim3(3, 400), 512, 0, stream>>>(P, nullptr, Bt0, bih0, nullptr, xW, 384, 384);
  k_gru<<<128, 512, 0, stream>>>(xW, Whh0, bhh0, H1);
  k_bn_mfma<4, 0, 0><<<dim3(3, 400), 512, 0, stream>>>(H1, nullptr, Bt1, bih1, nullptr, xW, 384, 384);
  k_gru<<<128, 512, 0, stream>>>(xW, Whh1, bhh1, H2);
  k_attn<<<6400, 128, 0, stream>>>(H2, inputs_f, embed_a, Katt);
  k_bn_mfma<8, 1, 2><<<dim3(3, 400), 512, 0, stream>>>(H2, Katt, Bt2, fc_b, mask_seqs, out, NC, NC);
}